// Round 24
// baseline (134.211 us; speedup 1.0000x reference)
//
#include <hip/hip_runtime.h>
#include <stdint.h>

#define N_EMBD 1024
#define NHEAD  16
#define HDIM   64
#define BATCH  8
#define SEQ    1024
#define MROWS  (BATCH*SEQ)   // 8192

typedef __bf16 bf16x8 __attribute__((ext_vector_type(8)));
typedef float  f32x4  __attribute__((ext_vector_type(4)));

__device__ inline unsigned short f2bf(float f) {
  uint32_t u = __float_as_uint(f);
  u += 0x7FFFu + ((u >> 16) & 1u);   // RNE; inputs are finite
  return (unsigned short)(u >> 16);
}

__device__ inline f32x4 mfma_bf16(bf16x8 a, bf16x8 b, f32x4 c) {
  return __builtin_amdgcn_mfma_f32_16x16x32_bf16(a, b, c, 0, 0, 0);
}

__device__ inline void gload_lds16(const unsigned short* g, unsigned short* l) {
  __builtin_amdgcn_global_load_lds(
      (const __attribute__((address_space(1))) void*)g,
      (__attribute__((address_space(3))) void*)l,
      16, 0, 0);
}

#define DSB __builtin_amdgcn_sched_barrier(0)
#define BARRIER __builtin_amdgcn_s_barrier()
#define VMC(n) asm volatile("s_waitcnt vmcnt(" #n ")" ::: "memory")
#define LGKM0 asm volatile("s_waitcnt lgkmcnt(0)" ::: "memory"); DSB

// ---------------- cast f32 -> bf16 (vectorized; HBM-roofline) ----------------
__global__ __launch_bounds__(256) void cast_f32_bf16(
    const float* __restrict__ in, unsigned short* __restrict__ out, int n) {
  int i = (blockIdx.x * 256 + threadIdx.x) * 4;
  if (i >= n) return;
  float4 v = *(const float4*)(in + i);
  ushort4 o;
  o.x = f2bf(v.x); o.y = f2bf(v.y); o.z = f2bf(v.z); o.w = f2bf(v.w);
  *(ushort4*)(out + i) = o;
}

// ---------------- merged transpose+cast for both weights ----------------
__global__ __launch_bounds__(256) void transpose_cast2(
    const float* __restrict__ wa, unsigned short* __restrict__ oa,
    const float* __restrict__ wp, unsigned short* __restrict__ op) {
  __shared__ unsigned short tile[64 * 72];
  const int K = 1024;
  int bx = blockIdx.x;
  const float* in; unsigned short* out; int N;
  if (bx < 48) { in = wa; out = oa; N = 3072; }
  else         { in = wp; out = op; N = 1024; bx -= 48; }
  int k0 = blockIdx.y * 64, n0 = bx * 64;
  int t = threadIdx.x;
  {
    int col = (t & 15) * 4;
#pragma unroll
    for (int it = 0; it < 4; ++it) {
      int row = (t >> 4) + it * 16;
      float4 v = *(const float4*)(in + (size_t)(k0 + row) * N + n0 + col);
      ushort4 o;
      o.x = f2bf(v.x); o.y = f2bf(v.y); o.z = f2bf(v.z); o.w = f2bf(v.w);
      *(ushort4*)&tile[row * 72 + col] = o;
    }
  }
  __syncthreads();
  {
    int kcol = (t & 7) * 8;
#pragma unroll
    for (int it = 0; it < 2; ++it) {
      int nrow = (t >> 3) + it * 32;
      alignas(16) unsigned short tmp[8];
#pragma unroll
      for (int j = 0; j < 8; ++j) tmp[j] = tile[(kcol + j) * 72 + nrow];
      *(uint4*)(out + (size_t)(n0 + nrow) * K + k0 + kcol) = *(const uint4*)tmp;
    }
  }
}

// ---------------- GEMM core: dbuf + counted vmcnt + STAGE-BEFORE-MFMA (T3 order) ----
// 128x128, BK=64, 4 waves, zero-conflict XOR swizzle. Per iter:
//   VMC(8) -> barrier -> ds_read buf[cur] -> lgkm0 -> barrier (buf free)
//   -> STAGE kt+2 into buf[cur] (issued BEFORE MFMA; MFMA covers flight) -> MFMA.
#define GEMM98_BODY(A_, Bt_)                                                    \
  __shared__ unsigned short Asl[2][8192];                                       \
  __shared__ unsigned short Bsl[2][8192];                                       \
  const int tid = threadIdx.x;                                                  \
  const int l = tid & 63, w = tid >> 6;                                         \
  const int wr = w >> 1, wc = w & 1;                                            \
  const int g = l >> 4, fr = l & 15;                                            \
  f32x4 acc[4][4];                                                              \
  _Pragma("unroll") for (int i = 0; i < 4; ++i)                                 \
    _Pragma("unroll") for (int j = 0; j < 4; ++j)                               \
      _Pragma("unroll") for (int r = 0; r < 4; ++r) acc[i][j][r] = 0.0f;        \
  const int rr = tid >> 3;                                                      \
  const int cs = ((tid & 7) * 16) ^ ((rr & 7) << 4);                            \
  const char* srcA[4]; const char* srcB[4];                                     \
  _Pragma("unroll") for (int c = 0; c < 4; ++c) {                               \
    srcA[c] = (const char*)(A_) + (size_t)(m0 + c * 32 + rr) * 2048 + cs;       \
    srcB[c] = (const char*)(Bt_) + (size_t)(n0 + c * 32 + rr) * 2048 + cs;      \
  }                                                                             \
  const int ldso = tid * 8;  /* shorts */                                       \
  const int arow = (wr * 64 + fr) * 128;                                        \
  const int brow = (wc * 64 + fr) * 128;                                        \
  int colk[2];                                                                  \
  colk[0] = (g * 16) ^ ((fr & 7) << 4);                                         \
  colk[1] = (64 + g * 16) ^ ((fr & 7) << 4);                                    \
  _Pragma("unroll") for (int c = 0; c < 4; ++c)                                 \
    gload_lds16((const unsigned short*)(srcA[c]), &Asl[0][ldso + c * 2048]);    \
  _Pragma("unroll") for (int c = 0; c < 4; ++c)                                 \
    gload_lds16((const unsigned short*)(srcB[c]), &Bsl[0][ldso + c * 2048]);    \
  _Pragma("unroll") for (int c = 0; c < 4; ++c)                                 \
    gload_lds16((const unsigned short*)(srcA[c] + 128), &Asl[1][ldso + c * 2048]);\
  _Pragma("unroll") for (int c = 0; c < 4; ++c)                                 \
    gload_lds16((const unsigned short*)(srcB[c] + 128), &Bsl[1][ldso + c * 2048]);\
  for (int kt = 0; kt < 16; ++kt) {                                             \
    const int cur = kt & 1;                                                     \
    if (kt < 15) { VMC(8); } else { VMC(0); }                                   \
    DSB; BARRIER; DSB;                                                          \
    bf16x8 av[2][4], bv[2][4];                                                  \
    _Pragma("unroll") for (int ks = 0; ks < 2; ++ks) {                          \
      _Pragma("unroll") for (int m = 0; m < 4; ++m)                             \
        av[ks][m] = *(const bf16x8*)((const char*)&Asl[cur][0] + arow +         \
                                     m * 16 * 128 + colk[ks]);                  \
      _Pragma("unroll") for (int n = 0; n < 4; ++n)                             \
        bv[ks][n] = *(const bf16x8*)((const char*)&Bsl[cur][0] + brow +         \
                                     n * 16 * 128 + colk[ks]);                  \
    }                                                                           \
    LGKM0; BARRIER; DSB;  /* all waves' reads of buf[cur] retired */            \
    if (kt < 14) {                                                              \
      const int ko = (kt + 2) * 128;                                            \
      _Pragma("unroll") for (int c = 0; c < 4; ++c)                             \
        gload_lds16((const unsigned short*)(srcA[c] + ko),                      \
                    &Asl[cur][ldso + c * 2048]);                                \
      _Pragma("unroll") for (int c = 0; c < 4; ++c)                             \
        gload_lds16((const unsigned short*)(srcB[c] + ko),                      \
                    &Bsl[cur][ldso + c * 2048]);                                \
    }                                                                           \
    __builtin_amdgcn_s_setprio(1);                                              \
    _Pragma("unroll") for (int ks = 0; ks < 2; ++ks)                            \
      _Pragma("unroll") for (int n = 0; n < 4; ++n)                             \
        _Pragma("unroll") for (int m = 0; m < 4; ++m)                           \
          acc[m][n] = mfma_bf16(av[ks][m], bv[ks][n], acc[m][n]);               \
    __builtin_amdgcn_s_setprio(0);                                              \
  }

// QKV GEMM: grid 1536, cache-shaped decode, coalesced LDS-staged epilogue.
__global__ __launch_bounds__(256) void gemm_qkv(
    const unsigned short* __restrict__ A, const unsigned short* __restrict__ Bt,
    const float* __restrict__ bias,
    unsigned short* __restrict__ Qo, unsigned short* __restrict__ Ko,
    unsigned short* __restrict__ VTo) {
  const int bid = blockIdx.x;
  const int xcd = bid & 7;
  const int local = bid >> 3;          // 0..191
  const int nchunk = local >> 6;       // 0..2
  const int rem = local & 63;
  const int m0 = (xcd * 8 + (rem >> 3)) * 128;
  const int n0 = (nchunk * 8 + (rem & 7)) * 128;
  GEMM98_BODY(A, Bt)
  const int nw0 = n0 + wc * 64;
  const int part = nw0 >> 10;
  const int h = (nw0 & 1023) >> 6;
  const int mw0 = m0 + wr * 64;
  const int bidx = mw0 >> 10;
  const int t0 = mw0 & 1023;
  unsigned short* stg = (w < 3) ? ((unsigned short*)Asl + w * 4608)
                                : ((unsigned short*)Bsl);
  float bvj[4];
#pragma unroll
  for (int j = 0; j < 4; ++j) bvj[j] = bias[nw0 + j * 16 + fr];
  if (part < 2) {
    const float scl = (part == 0) ? 0.125f : 1.0f;  // fold 1/sqrt(hd) into Q
#pragma unroll
    for (int i = 0; i < 4; ++i)
#pragma unroll
      for (int j = 0; j < 4; ++j)
#pragma unroll
        for (int r = 0; r < 4; ++r)
          stg[(i * 16 + 4 * g + r) * 72 + j * 16 + fr] =
              f2bf((acc[i][j][r] + bvj[j]) * scl);
    LGKM0;
    unsigned short* dst = (part == 0) ? Qo : Ko;
    size_t base = ((size_t)(bidx * NHEAD + h) * SEQ + t0) * HDIM + (l & 7) * 8;
#pragma unroll
    for (int it = 0; it < 8; ++it) {
      int row = (l >> 3) + it * 8;
      uint4 v = *(const uint4*)&stg[row * 72 + (l & 7) * 8];
      *(uint4*)&dst[base + (size_t)row * HDIM] = v;
    }
  } else {
#pragma unroll
    for (int i = 0; i < 4; ++i)
#pragma unroll
      for (int j = 0; j < 4; ++j)
#pragma unroll
        for (int r = 0; r < 4; ++r)
          stg[(j * 16 + fr) * 72 + i * 16 + 4 * g + r] =
              f2bf(acc[i][j][r] + bvj[j]);
    LGKM0;
    size_t base = ((size_t)(bidx * NHEAD + h) * HDIM) * SEQ + t0 + (l & 7) * 8;
#pragma unroll
    for (int it = 0; it < 8; ++it) {
      int row = (l >> 3) + it * 8;   // d
      uint4 v = *(const uint4*)&stg[row * 72 + (l & 7) * 8];
      *(uint4*)&VTo[base + (size_t)row * SEQ] = v;
    }
  }
}

// Proj GEMM: grid 512, cache-shaped decode, plain f32 epilogue.
__global__ __launch_bounds__(256) void gemm_proj(
    const unsigned short* __restrict__ A, const unsigned short* __restrict__ Bt,
    const float* __restrict__ bias, float* __restrict__ Out) {
  const int bid = blockIdx.x;
  const int xcd = bid & 7;
  const int local = bid >> 3;          // 0..63
  const int m0 = (xcd * 8 + (local >> 3)) * 128;
  const int n0 = (local & 7) * 128;
  GEMM98_BODY(A, Bt)
#pragma unroll
  for (int i = 0; i < 4; ++i) {
    int mb = m0 + wr * 64 + i * 16 + 4 * g;
#pragma unroll
    for (int j = 0; j < 4; ++j) {
      int n = n0 + wc * 64 + j * 16 + fr;
      float bv2 = bias[n];
#pragma unroll
      for (int r = 0; r < 4; ++r)
        Out[(size_t)(mb + r) * N_EMBD + n] = acc[i][j][r] + bv2;
    }
  }
}

// ---------------- flash attention v2 (__expf, mrun=0, threshold 8) ----------------
__global__ __launch_bounds__(256) void attn_kernel(
    const unsigned short* __restrict__ Q, const unsigned short* __restrict__ Kv,
    const unsigned short* __restrict__ VT, unsigned short* __restrict__ Y) {
  __shared__ unsigned short Kt[2][4096];
  __shared__ unsigned short Vt[2][4096];
  __shared__ unsigned short p_lds[4 * 32 * 72];
  __shared__ float smx[4][32];
  int tid = threadIdx.x, l = tid & 63, w = tid >> 6;
  int bid = blockIdx.x;
  int swz = (bid & 7) * 64 + (bid >> 3);   // bijective (512 % 8 == 0)
  int bh = swz >> 2;
  int pairIdx = swz & 3;
  int b = bh >> 4, h = bh & 15;
  const unsigned short* Qb = Q + (size_t)bh * SEQ * HDIM;
  const char* Kc = (const char*)(Kv + (size_t)bh * SEQ * HDIM);
  const char* Vc = (const char*)(VT + (size_t)bh * HDIM * SEQ);
  unsigned short* pw = &p_lds[w * 32 * 72];
  const int g = l >> 4;
  const int fr = l & 15;

  const int P0 = tid * 16, P1 = tid * 16 + 4096;
  const int r0 = P0 >> 7, r1 = P1 >> 7;
  const int s0 = (P0 & 127) ^ ((r0 & 7) << 4);
  const int s1 = (P1 & 127) ^ ((r1 & 7) << 4);
  const char* Kg0 = Kc + r0 * 128 + s0;
  const char* Kg1 = Kc + r1 * 128 + s1;
  const char* Vg0 = Vc + (size_t)r0 * 2048 + s0;
  const char* Vg1 = Vc + (size_t)r1 * 2048 + s1;

  const int bc = (16 * g) ^ ((l & 7) << 4);

  for (int part = 0; part < 2; ++part) {
    const int qt = (part == 0) ? pairIdx : 7 - pairIdx;
    const int q0 = qt * 128;
    const int wq = q0 + w * 32;

    bf16x8 aq[2][2];
#pragma unroll
    for (int i = 0; i < 2; ++i)
#pragma unroll
      for (int ik = 0; ik < 2; ++ik)
        aq[i][ik] = *(const bf16x8*)&Qb[(size_t)(wq + i * 16 + fr) * HDIM + ik * 32 + 8 * g];

    float mrun[2], lpart[2];
    mrun[0] = mrun[1] = 0.0f;
    lpart[0] = lpart[1] = 0.0f;
    f32x4 acc_o[2][4];
#pragma unroll
    for (int i = 0; i < 2; ++i)
#pragma unroll
      for (int jd = 0; jd < 4; ++jd)
#pragma unroll
        for (int r = 0; r < 4; ++r) acc_o[i][jd][r] = 0.0f;

    const int n_it = (q0 + 128) >> 6;

    gload_lds16((const unsigned short*)(Kg0), &Kt[0][P0 >> 1]);
    gload_lds16((const unsigned short*)(Kg1), &Kt[0][P1 >> 1]);
    gload_lds16((const unsigned short*)(Vg0), &Vt[0][P0 >> 1]);
    gload_lds16((const unsigned short*)(Vg1), &Vt[0][P1 >> 1]);

    for (int it = 0; it < n_it; ++it) {
      const int kv0 = it << 6;
      const int cur = it & 1;
      if (it + 1 < n_it) {
        const int nx = kv0 + 64;
        gload_lds16((const unsigned short*)(Kg0 + nx * 128), &Kt[cur ^ 1][P0 >> 1]);
        gload_lds16((const unsigned short*)(Kg1 + nx * 128), &Kt[cur ^ 1][P1 >> 1]);
        gload_lds16((const unsigned short*)(Vg0 + nx * 2),   &Vt[cur ^ 1][P0 >> 1]);
        gload_lds16((const unsigned short*)(Vg1 + nx * 2),   &Vt[cur ^ 1][P1 >> 1]);
        VMC(4);
      } else {
        VMC(0);
      }
      DSB; BARRIER; DSB;

      const char* Kbuf = (const char*)Kt[cur];
      const char* Vbuf = (const char*)Vt[cur];

      f32x4 s2[2][4];
#pragma unroll
      for (int i = 0; i < 2; ++i)
#pragma unroll
        for (int j = 0; j < 4; ++j)
#pragma unroll
          for (int r = 0; r < 4; ++r) s2[i][j][r] = 0.0f;

      __builtin_amdgcn_s_setprio(1);
#pragma unroll
      for (int ik = 0; ik < 2; ++ik) {
#pragma unroll
        for (int j = 0; j < 4; ++j) {
          bf16x8 bk = *(const bf16x8*)(Kbuf + (j * 16 + fr) * 128 + (bc ^ (ik << 6)));
#pragma unroll
          for (int i = 0; i < 2; ++i) s2[i][j] = mfma_bf16(bk, aq[i][ik], s2[i][j]);
        }
      }
      __builtin_amdgcn_s_setprio(0);

      bool need_mask = (kv0 + 63) > wq;
      if (need_mask) {
#pragma unroll
        for (int i = 0; i < 2; ++i) {
          int q = wq + i * 16 + fr;
#pragma unroll
          for (int j = 0; j < 4; ++j)
#pragma unroll
            for (int r = 0; r < 4; ++r) {
              int kv = kv0 + j * 16 + 4 * g + r;
              if (kv > q) s2[i][j][r] = -3.0e38f;
            }
        }
      }

      float pmloc[2];
#pragma unroll
      for (int i = 0; i < 2; ++i) {
        float m01 = fmaxf(fmaxf(s2[i][0][0], s2[i][0][1]), fmaxf(s2[i][0][2], s2[i][0][3]));
        float m11 = fmaxf(fmaxf(s2[i][1][0], s2[i][1][1]), fmaxf(s2[i][1][2], s2[i][1][3]));
        float m21 = fmaxf(fmaxf(s2[i][2][0], s2[i][2][1]), fmaxf(s2[i][2][2], s2[i][2][3]));
        float m31 = fmaxf(fmaxf(s2[i][3][0], s2[i][3][1]), fmaxf(s2[i][3][2], s2[i][3][3]));
        pmloc[i] = fmaxf(fmaxf(m01, m11), fmaxf(m21, m31));
      }
      bool ok = (pmloc[0] <= mrun[0] + 8.0f) && (pmloc[1] <= mrun[1] + 8.0f);
      if (!__all(ok)) {   // rare: full reduce + rescale
#pragma unroll
        for (int i = 0; i < 2; ++i) {
          float mm = pmloc[i];
          mm = fmaxf(mm, __shfl_xor(mm, 16, 64));
          mm = fmaxf(mm, __shfl_xor(mm, 32, 64));
          float mn = fmaxf(mrun[i], mm);
          float sc = __expf(mrun[i] - mn);
          mrun[i] = mn;
          lpart[i] *= sc;
          if (g == 0) smx[w][i * 16 + fr] = sc;
        }
        asm volatile("s_waitcnt lgkmcnt(0)" ::: "memory");
#pragma unroll
        for (int i = 0; i < 2; ++i)
#pragma unroll
          for (int r = 0; r < 4; ++r) {
            float sc = smx[w][i * 16 + 4 * g + r];
#pragma unroll
            for (int jd = 0; jd < 4; ++jd) acc_o[i][jd][r] *= sc;
          }
      }

#pragma unroll
      for (int i = 0; i < 2; ++i) {
#pragma unroll
        for (int j = 0; j < 4; ++j) {
          float p0 = __expf(s2[i][j][0] - mrun[i]);
          float p1 = __expf(s2[i][j][1] - mrun[i]);
          float p2 = __expf(s2[i][j][2] - mrun[i]);
          float p3 = __expf(s2[i][j][3] - mrun[i]);
          lpart[i] += (p0 + p1) + (p2 + p3);
          uint2 pk2;
          asm("v_cvt_pk_bf16_f32 %0, %1, %2" : "=v"(pk2.x) : "v"(p0), "v"(p1));
          asm("v_cvt_pk_bf16_f32 %0, %1, %2" : "=v"(pk2.y) : "v"(p2), "v"(p3));
          *(uint2*)&pw[(i * 16 + fr) * 72 + j * 16 + 4 * g] = pk2;
        }
      }

      __builtin_amdgcn_s_setprio(1);
#pragma unroll
      for (int ik2 = 0; ik2 < 2; ++ik2) {
        bf16x8 ap[2];
#pragma unroll
        for (int i = 0; i < 2; ++i)
          ap[i] = *(const bf16x8*)&pw[(i * 16 + fr) * 72 + ik2 * 32 + 8 * g];
#pragma unroll
        for (int jd = 0; jd < 4; ++jd) {
          bf16x8 bv = *(const bf16x8*)(Vbuf + (jd * 16 + fr) * 128 + (bc ^ (ik2 << 6)));
#pragma unroll
          for (int i = 0; i < 2; ++i) acc_o[i][jd] = mfma_bf16(ap[i], bv, acc_o[i][jd]);
        }
      }
      __builtin_amdgcn_s_setprio(0);

      asm volatile("s_waitcnt lgkmcnt(0)" ::: "memory");
      DSB; BARRIER; DSB;
    }

#pragma unroll
    for (int i = 0; i < 2; ++i) {
      float t = lpart[i];
      t += __shfl_xor(t, 16, 64);
      t += __shfl_xor(t, 32, 64);
      if (g == 0) smx[w][i * 16 + fr] = t;
    }
    asm volatile("s_waitcnt lgkmcnt(0)" ::: "memory");
#pragma unroll
    for (int i = 0; i < 2; ++i)
#pragma unroll
      for (int r = 0; r < 4; ++r) {
        float inv = 1.0f / smx[w][i * 16 + 4 * g + r];
        int q = wq + i * 16 + 4 * g + r;
#pragma unroll
        for (int jd = 0; jd < 4; ++jd)
          Y[((size_t)b * SEQ + q) * N_EMBD + h * HDIM + jd * 16 + fr] =
              f2bf(acc_o[i][jd][r] * inv);
      }
  }
}

// ---------------- launcher ----------------
extern "C" void kernel_launch(void* const* d_in, const int* in_sizes, int n_in,
                              void* d_out, int out_size, void* d_ws, size_t ws_size,
                              hipStream_t stream) {
  (void)in_sizes; (void)n_in; (void)out_size; (void)ws_size;
  const float* x      = (const float*)d_in[0];
  const float* w_attn = (const float*)d_in[1];
  const float* b_attn = (const float*)d_in[2];
  const float* w_proj = (const float*)d_in[3];
  const float* b_proj = (const float*)d_in[4];
  float* out = (float*)d_out;

  char* ws = (char*)d_ws;
  size_t off = 0;
  auto carve = [&](size_t bytes) -> char* {
    char* p = ws + off;
    off += (bytes + 255) & ~(size_t)255;
    return p;
  };
  unsigned short* xb     = (unsigned short*)carve((size_t)MROWS * N_EMBD * 2);
  unsigned short* wTattn = (unsigned short*)carve((size_t)3 * N_EMBD * N_EMBD * 2);
  unsigned short* wTproj = (unsigned short*)carve((size_t)N_EMBD * N_EMBD * 2);
  unsigned short* Qb     = (unsigned short*)carve((size_t)MROWS * N_EMBD * 2);
  unsigned short* Kb     = (unsigned short*)carve((size_t)MROWS * N_EMBD * 2);
  unsigned short* VTb    = (unsigned short*)carve((size_t)MROWS * N_EMBD * 2);
  unsigned short* Yb     = (unsigned short*)carve((size_t)MROWS * N_EMBD * 2);
  carve(4096);

  cast_f32_bf16<<<dim3(MROWS * N_EMBD / 1024), 256, 0, stream>>>(x, xb, MROWS * N_EMBD);
  transpose_cast2<<<dim3(64, 16), 256, 0, stream>>>(w_attn, wTattn, w_proj, wTproj);
  gemm_qkv<<<dim3(1536), 256, 0, stream>>>(xb, wTattn, b_attn, Qb, Kb, VTb);
  attn_kernel<<<dim3(512), 256, 0, stream>>>(Qb, Kb, VTb, Yb);
  gemm_proj<<<dim3(512), 256, 0, stream>>>(Yb, wTproj, b_proj, out);
}

// Round 25
// 133.747 us; speedup vs baseline: 1.0035x; 1.0035x over previous
//
#include <hip/hip_runtime.h>
#include <stdint.h>

#define N_EMBD 1024
#define NHEAD  16
#define HDIM   64
#define BATCH  8
#define SEQ    1024
#define MROWS  (BATCH*SEQ)   // 8192

typedef __bf16 bf16x8 __attribute__((ext_vector_type(8)));
typedef float  f32x4  __attribute__((ext_vector_type(4)));

__device__ inline unsigned short f2bf(float f) {
  uint32_t u = __float_as_uint(f);
  u += 0x7FFFu + ((u >> 16) & 1u);   // RNE; inputs are finite
  return (unsigned short)(u >> 16);
}

__device__ inline f32x4 mfma_bf16(bf16x8 a, bf16x8 b, f32x4 c) {
  return __builtin_amdgcn_mfma_f32_16x16x32_bf16(a, b, c, 0, 0, 0);
}

__device__ inline void gload_lds16(const unsigned short* g, unsigned short* l) {
  __builtin_amdgcn_global_load_lds(
      (const __attribute__((address_space(1))) void*)g,
      (__attribute__((address_space(3))) void*)l,
      16, 0, 0);
}

#define DSB __builtin_amdgcn_sched_barrier(0)
#define BARRIER __builtin_amdgcn_s_barrier()
#define VMC(n) asm volatile("s_waitcnt vmcnt(" #n ")" ::: "memory")
#define LGKM0 asm volatile("s_waitcnt lgkmcnt(0)" ::: "memory"); DSB

// ---------------- cast f32 -> bf16 (vectorized; HBM-roofline) ----------------
__global__ __launch_bounds__(256) void cast_f32_bf16(
    const float* __restrict__ in, unsigned short* __restrict__ out, int n) {
  int i = (blockIdx.x * 256 + threadIdx.x) * 4;
  if (i >= n) return;
  float4 v = *(const float4*)(in + i);
  ushort4 o;
  o.x = f2bf(v.x); o.y = f2bf(v.y); o.z = f2bf(v.z); o.w = f2bf(v.w);
  *(ushort4*)(out + i) = o;
}

// ---------------- merged transpose+cast for both weights ----------------
__global__ __launch_bounds__(256) void transpose_cast2(
    const float* __restrict__ wa, unsigned short* __restrict__ oa,
    const float* __restrict__ wp, unsigned short* __restrict__ op) {
  __shared__ unsigned short tile[64 * 72];
  const int K = 1024;
  int bx = blockIdx.x;
  const float* in; unsigned short* out; int N;
  if (bx < 48) { in = wa; out = oa; N = 3072; }
  else         { in = wp; out = op; N = 1024; bx -= 48; }
  int k0 = blockIdx.y * 64, n0 = bx * 64;
  int t = threadIdx.x;
  {
    int col = (t & 15) * 4;
#pragma unroll
    for (int it = 0; it < 4; ++it) {
      int row = (t >> 4) + it * 16;
      float4 v = *(const float4*)(in + (size_t)(k0 + row) * N + n0 + col);
      ushort4 o;
      o.x = f2bf(v.x); o.y = f2bf(v.y); o.z = f2bf(v.z); o.w = f2bf(v.w);
      *(ushort4*)&tile[row * 72 + col] = o;
    }
  }
  __syncthreads();
  {
    int kcol = (t & 7) * 8;
#pragma unroll
    for (int it = 0; it < 2; ++it) {
      int nrow = (t >> 3) + it * 32;
      alignas(16) unsigned short tmp[8];
#pragma unroll
      for (int j = 0; j < 8; ++j) tmp[j] = tile[(kcol + j) * 72 + nrow];
      *(uint4*)(out + (size_t)(n0 + nrow) * K + k0 + kcol) = *(const uint4*)tmp;
    }
  }
}

// ---------------- GEMM core: dbuf + counted vmcnt + STAGE-BEFORE-MFMA (T3 order) ----
// 128x128, BK=64, 4 waves, zero-conflict XOR swizzle. Per iter:
//   VMC(8) -> barrier -> ds_read buf[cur] -> lgkm0 -> barrier (buf free)
//   -> STAGE kt+2 into buf[cur] (issued BEFORE MFMA; MFMA covers flight) -> MFMA.
#define GEMM98_BODY(A_, Bt_)                                                    \
  __shared__ unsigned short Asl[2][8192];                                       \
  __shared__ unsigned short Bsl[2][8192];                                       \
  const int tid = threadIdx.x;                                                  \
  const int l = tid & 63, w = tid >> 6;                                         \
  const int wr = w >> 1, wc = w & 1;                                            \
  const int g = l >> 4, fr = l & 15;                                            \
  f32x4 acc[4][4];                                                              \
  _Pragma("unroll") for (int i = 0; i < 4; ++i)                                 \
    _Pragma("unroll") for (int j = 0; j < 4; ++j)                               \
      _Pragma("unroll") for (int r = 0; r < 4; ++r) acc[i][j][r] = 0.0f;        \
  const int rr = tid >> 3;                                                      \
  const int cs = ((tid & 7) * 16) ^ ((rr & 7) << 4);                            \
  const char* srcA[4]; const char* srcB[4];                                     \
  _Pragma("unroll") for (int c = 0; c < 4; ++c) {                               \
    srcA[c] = (const char*)(A_) + (size_t)(m0 + c * 32 + rr) * 2048 + cs;       \
    srcB[c] = (const char*)(Bt_) + (size_t)(n0 + c * 32 + rr) * 2048 + cs;      \
  }                                                                             \
  const int ldso = tid * 8;  /* shorts */                                       \
  const int arow = (wr * 64 + fr) * 128;                                        \
  const int brow = (wc * 64 + fr) * 128;                                        \
  int colk[2];                                                                  \
  colk[0] = (g * 16) ^ ((fr & 7) << 4);                                         \
  colk[1] = (64 + g * 16) ^ ((fr & 7) << 4);                                    \
  _Pragma("unroll") for (int c = 0; c < 4; ++c)                                 \
    gload_lds16((const unsigned short*)(srcA[c]), &Asl[0][ldso + c * 2048]);    \
  _Pragma("unroll") for (int c = 0; c < 4; ++c)                                 \
    gload_lds16((const unsigned short*)(srcB[c]), &Bsl[0][ldso + c * 2048]);    \
  _Pragma("unroll") for (int c = 0; c < 4; ++c)                                 \
    gload_lds16((const unsigned short*)(srcA[c] + 128), &Asl[1][ldso + c * 2048]);\
  _Pragma("unroll") for (int c = 0; c < 4; ++c)                                 \
    gload_lds16((const unsigned short*)(srcB[c] + 128), &Bsl[1][ldso + c * 2048]);\
  for (int kt = 0; kt < 16; ++kt) {                                             \
    const int cur = kt & 1;                                                     \
    if (kt < 15) { VMC(8); } else { VMC(0); }                                   \
    DSB; BARRIER; DSB;                                                          \
    bf16x8 av[2][4], bv[2][4];                                                  \
    _Pragma("unroll") for (int ks = 0; ks < 2; ++ks) {                          \
      _Pragma("unroll") for (int m = 0; m < 4; ++m)                             \
        av[ks][m] = *(const bf16x8*)((const char*)&Asl[cur][0] + arow +         \
                                     m * 16 * 128 + colk[ks]);                  \
      _Pragma("unroll") for (int n = 0; n < 4; ++n)                             \
        bv[ks][n] = *(const bf16x8*)((const char*)&Bsl[cur][0] + brow +         \
                                     n * 16 * 128 + colk[ks]);                  \
    }                                                                           \
    LGKM0; BARRIER; DSB;  /* all waves' reads of buf[cur] retired */            \
    if (kt < 14) {                                                              \
      const int ko = (kt + 2) * 128;                                            \
      _Pragma("unroll") for (int c = 0; c < 4; ++c)                             \
        gload_lds16((const unsigned short*)(srcA[c] + ko),                      \
                    &Asl[cur][ldso + c * 2048]);                                \
      _Pragma("unroll") for (int c = 0; c < 4; ++c)                             \
        gload_lds16((const unsigned short*)(srcB[c] + ko),                      \
                    &Bsl[cur][ldso + c * 2048]);                                \
    }                                                                           \
    __builtin_amdgcn_s_setprio(1);                                              \
    _Pragma("unroll") for (int ks = 0; ks < 2; ++ks)                            \
      _Pragma("unroll") for (int n = 0; n < 4; ++n)                             \
        _Pragma("unroll") for (int m = 0; m < 4; ++m)                           \
          acc[m][n] = mfma_bf16(av[ks][m], bv[ks][n], acc[m][n]);               \
    __builtin_amdgcn_s_setprio(0);                                              \
  }

// QKV GEMM: grid 1536, cache-shaped decode, coalesced LDS-staged epilogue.
__global__ __launch_bounds__(256) void gemm_qkv(
    const unsigned short* __restrict__ A, const unsigned short* __restrict__ Bt,
    const float* __restrict__ bias,
    unsigned short* __restrict__ Qo, unsigned short* __restrict__ Ko,
    unsigned short* __restrict__ VTo) {
  const int bid = blockIdx.x;
  const int xcd = bid & 7;
  const int local = bid >> 3;          // 0..191
  const int nchunk = local >> 6;       // 0..2
  const int rem = local & 63;
  const int m0 = (xcd * 8 + (rem >> 3)) * 128;
  const int n0 = (nchunk * 8 + (rem & 7)) * 128;
  GEMM98_BODY(A, Bt)
  const int nw0 = n0 + wc * 64;
  const int part = nw0 >> 10;
  const int h = (nw0 & 1023) >> 6;
  const int mw0 = m0 + wr * 64;
  const int bidx = mw0 >> 10;
  const int t0 = mw0 & 1023;
  unsigned short* stg = (w < 3) ? ((unsigned short*)Asl + w * 4608)
                                : ((unsigned short*)Bsl);
  float bvj[4];
#pragma unroll
  for (int j = 0; j < 4; ++j) bvj[j] = bias[nw0 + j * 16 + fr];
  if (part < 2) {
    const float scl = (part == 0) ? 0.125f : 1.0f;  // fold 1/sqrt(hd) into Q
#pragma unroll
    for (int i = 0; i < 4; ++i)
#pragma unroll
      for (int j = 0; j < 4; ++j)
#pragma unroll
        for (int r = 0; r < 4; ++r)
          stg[(i * 16 + 4 * g + r) * 72 + j * 16 + fr] =
              f2bf((acc[i][j][r] + bvj[j]) * scl);
    LGKM0;
    unsigned short* dst = (part == 0) ? Qo : Ko;
    size_t base = ((size_t)(bidx * NHEAD + h) * SEQ + t0) * HDIM + (l & 7) * 8;
#pragma unroll
    for (int it = 0; it < 8; ++it) {
      int row = (l >> 3) + it * 8;
      uint4 v = *(const uint4*)&stg[row * 72 + (l & 7) * 8];
      *(uint4*)&dst[base + (size_t)row * HDIM] = v;
    }
  } else {
#pragma unroll
    for (int i = 0; i < 4; ++i)
#pragma unroll
      for (int j = 0; j < 4; ++j)
#pragma unroll
        for (int r = 0; r < 4; ++r)
          stg[(j * 16 + fr) * 72 + i * 16 + 4 * g + r] =
              f2bf(acc[i][j][r] + bvj[j]);
    LGKM0;
    size_t base = ((size_t)(bidx * NHEAD + h) * HDIM) * SEQ + t0 + (l & 7) * 8;
#pragma unroll
    for (int it = 0; it < 8; ++it) {
      int row = (l >> 3) + it * 8;   // d
      uint4 v = *(const uint4*)&stg[row * 72 + (l & 7) * 8];
      *(uint4*)&VTo[base + (size_t)row * SEQ] = v;
    }
  }
}

// Proj GEMM: grid 512, cache-shaped decode, plain f32 epilogue.
__global__ __launch_bounds__(256) void gemm_proj(
    const unsigned short* __restrict__ A, const unsigned short* __restrict__ Bt,
    const float* __restrict__ bias, float* __restrict__ Out) {
  const int bid = blockIdx.x;
  const int xcd = bid & 7;
  const int local = bid >> 3;          // 0..63
  const int m0 = (xcd * 8 + (local >> 3)) * 128;
  const int n0 = (local & 7) * 128;
  GEMM98_BODY(A, Bt)
#pragma unroll
  for (int i = 0; i < 4; ++i) {
    int mb = m0 + wr * 64 + i * 16 + 4 * g;
#pragma unroll
    for (int j = 0; j < 4; ++j) {
      int n = n0 + wc * 64 + j * 16 + fr;
      float bv2 = bias[n];
#pragma unroll
      for (int r = 0; r < 4; ++r)
        Out[(size_t)(mb + r) * N_EMBD + n] = acc[i][j][r] + bv2;
    }
  }
}

// ---------------- flash attention v2 (__expf, mrun=0, threshold 8) ----------------
__global__ __launch_bounds__(256) void attn_kernel(
    const unsigned short* __restrict__ Q, const unsigned short* __restrict__ Kv,
    const unsigned short* __restrict__ VT, unsigned short* __restrict__ Y) {
  __shared__ unsigned short Kt[2][4096];
  __shared__ unsigned short Vt[2][4096];
  __shared__ unsigned short p_lds[4 * 32 * 72];
  __shared__ float smx[4][32];
  int tid = threadIdx.x, l = tid & 63, w = tid >> 6;
  int bid = blockIdx.x;
  int swz = (bid & 7) * 64 + (bid >> 3);   // bijective (512 % 8 == 0)
  int bh = swz >> 2;
  int pairIdx = swz & 3;
  int b = bh >> 4, h = bh & 15;
  const unsigned short* Qb = Q + (size_t)bh * SEQ * HDIM;
  const char* Kc = (const char*)(Kv + (size_t)bh * SEQ * HDIM);
  const char* Vc = (const char*)(VT + (size_t)bh * HDIM * SEQ);
  unsigned short* pw = &p_lds[w * 32 * 72];
  const int g = l >> 4;
  const int fr = l & 15;

  const int P0 = tid * 16, P1 = tid * 16 + 4096;
  const int r0 = P0 >> 7, r1 = P1 >> 7;
  const int s0 = (P0 & 127) ^ ((r0 & 7) << 4);
  const int s1 = (P1 & 127) ^ ((r1 & 7) << 4);
  const char* Kg0 = Kc + r0 * 128 + s0;
  const char* Kg1 = Kc + r1 * 128 + s1;
  const char* Vg0 = Vc + (size_t)r0 * 2048 + s0;
  const char* Vg1 = Vc + (size_t)r1 * 2048 + s1;

  const int bc = (16 * g) ^ ((l & 7) << 4);

  for (int part = 0; part < 2; ++part) {
    const int qt = (part == 0) ? pairIdx : 7 - pairIdx;
    const int q0 = qt * 128;
    const int wq = q0 + w * 32;

    bf16x8 aq[2][2];
#pragma unroll
    for (int i = 0; i < 2; ++i)
#pragma unroll
      for (int ik = 0; ik < 2; ++ik)
        aq[i][ik] = *(const bf16x8*)&Qb[(size_t)(wq + i * 16 + fr) * HDIM + ik * 32 + 8 * g];

    float mrun[2], lpart[2];
    mrun[0] = mrun[1] = 0.0f;
    lpart[0] = lpart[1] = 0.0f;
    f32x4 acc_o[2][4];
#pragma unroll
    for (int i = 0; i < 2; ++i)
#pragma unroll
      for (int jd = 0; jd < 4; ++jd)
#pragma unroll
        for (int r = 0; r < 4; ++r) acc_o[i][jd][r] = 0.0f;

    const int n_it = (q0 + 128) >> 6;

    gload_lds16((const unsigned short*)(Kg0), &Kt[0][P0 >> 1]);
    gload_lds16((const unsigned short*)(Kg1), &Kt[0][P1 >> 1]);
    gload_lds16((const unsigned short*)(Vg0), &Vt[0][P0 >> 1]);
    gload_lds16((const unsigned short*)(Vg1), &Vt[0][P1 >> 1]);

    for (int it = 0; it < n_it; ++it) {
      const int kv0 = it << 6;
      const int cur = it & 1;
      if (it + 1 < n_it) {
        const int nx = kv0 + 64;
        gload_lds16((const unsigned short*)(Kg0 + nx * 128), &Kt[cur ^ 1][P0 >> 1]);
        gload_lds16((const unsigned short*)(Kg1 + nx * 128), &Kt[cur ^ 1][P1 >> 1]);
        gload_lds16((const unsigned short*)(Vg0 + nx * 2),   &Vt[cur ^ 1][P0 >> 1]);
        gload_lds16((const unsigned short*)(Vg1 + nx * 2),   &Vt[cur ^ 1][P1 >> 1]);
        VMC(4);
      } else {
        VMC(0);
      }
      DSB; BARRIER; DSB;

      const char* Kbuf = (const char*)Kt[cur];
      const char* Vbuf = (const char*)Vt[cur];

      f32x4 s2[2][4];
#pragma unroll
      for (int i = 0; i < 2; ++i)
#pragma unroll
        for (int j = 0; j < 4; ++j)
#pragma unroll
          for (int r = 0; r < 4; ++r) s2[i][j][r] = 0.0f;

      __builtin_amdgcn_s_setprio(1);
#pragma unroll
      for (int ik = 0; ik < 2; ++ik) {
#pragma unroll
        for (int j = 0; j < 4; ++j) {
          bf16x8 bk = *(const bf16x8*)(Kbuf + (j * 16 + fr) * 128 + (bc ^ (ik << 6)));
#pragma unroll
          for (int i = 0; i < 2; ++i) s2[i][j] = mfma_bf16(bk, aq[i][ik], s2[i][j]);
        }
      }
      __builtin_amdgcn_s_setprio(0);

      bool need_mask = (kv0 + 63) > wq;
      if (need_mask) {
#pragma unroll
        for (int i = 0; i < 2; ++i) {
          int q = wq + i * 16 + fr;
#pragma unroll
          for (int j = 0; j < 4; ++j)
#pragma unroll
            for (int r = 0; r < 4; ++r) {
              int kv = kv0 + j * 16 + 4 * g + r;
              if (kv > q) s2[i][j][r] = -3.0e38f;
            }
        }
      }

      float pmloc[2];
#pragma unroll
      for (int i = 0; i < 2; ++i) {
        float m01 = fmaxf(fmaxf(s2[i][0][0], s2[i][0][1]), fmaxf(s2[i][0][2], s2[i][0][3]));
        float m11 = fmaxf(fmaxf(s2[i][1][0], s2[i][1][1]), fmaxf(s2[i][1][2], s2[i][1][3]));
        float m21 = fmaxf(fmaxf(s2[i][2][0], s2[i][2][1]), fmaxf(s2[i][2][2], s2[i][2][3]));
        float m31 = fmaxf(fmaxf(s2[i][3][0], s2[i][3][1]), fmaxf(s2[i][3][2], s2[i][3][3]));
        pmloc[i] = fmaxf(fmaxf(m01, m11), fmaxf(m21, m31));
      }
      bool ok = (pmloc[0] <= mrun[0] + 8.0f) && (pmloc[1] <= mrun[1] + 8.0f);
      if (!__all(ok)) {   // rare: full reduce + rescale
#pragma unroll
        for (int i = 0; i < 2; ++i) {
          float mm = pmloc[i];
          mm = fmaxf(mm, __shfl_xor(mm, 16, 64));
          mm = fmaxf(mm, __shfl_xor(mm, 32, 64));
          float mn = fmaxf(mrun[i], mm);
          float sc = __expf(mrun[i] - mn);
          mrun[i] = mn;
          lpart[i] *= sc;
          if (g == 0) smx[w][i * 16 + fr] = sc;
        }
        asm volatile("s_waitcnt lgkmcnt(0)" ::: "memory");
#pragma unroll
        for (int i = 0; i < 2; ++i)
#pragma unroll
          for (int r = 0; r < 4; ++r) {
            float sc = smx[w][i * 16 + 4 * g + r];
#pragma unroll
            for (int jd = 0; jd < 4; ++jd) acc_o[i][jd][r] *= sc;
          }
      }

#pragma unroll
      for (int i = 0; i < 2; ++i) {
#pragma unroll
        for (int j = 0; j < 4; ++j) {
          float p0 = __expf(s2[i][j][0] - mrun[i]);
          float p1 = __expf(s2[i][j][1] - mrun[i]);
          float p2 = __expf(s2[i][j][2] - mrun[i]);
          float p3 = __expf(s2[i][j][3] - mrun[i]);
          lpart[i] += (p0 + p1) + (p2 + p3);
          uint2 pk2;
          asm("v_cvt_pk_bf16_f32 %0, %1, %2" : "=v"(pk2.x) : "v"(p0), "v"(p1));
          asm("v_cvt_pk_bf16_f32 %0, %1, %2" : "=v"(pk2.y) : "v"(p2), "v"(p3));
          *(uint2*)&pw[(i * 16 + fr) * 72 + j * 16 + 4 * g] = pk2;
        }
      }

      __builtin_amdgcn_s_setprio(1);
#pragma unroll
      for (int ik2 = 0; ik2 < 2; ++ik2) {
        bf16x8 ap[2];
#pragma unroll
        for (int i = 0; i < 2; ++i)
          ap[i] = *(const bf16x8*)&pw[(i * 16 + fr) * 72 + ik2 * 32 + 8 * g];
#pragma unroll
        for (int jd = 0; jd < 4; ++jd) {
          bf16x8 bv = *(const bf16x8*)(Vbuf + (jd * 16 + fr) * 128 + (bc ^ (ik2 << 6)));
#pragma unroll
          for (int i = 0; i < 2; ++i) acc_o[i][jd] = mfma_bf16(ap[i], bv, acc_o[i][jd]);
        }
      }
      __builtin_amdgcn_s_setprio(0);

      asm volatile("s_waitcnt lgkmcnt(0)" ::: "memory");
      DSB; BARRIER; DSB;
    }

#pragma unroll
    for (int i = 0; i < 2; ++i) {
      float t = lpart[i];
      t += __shfl_xor(t, 16, 64);
      t += __shfl_xor(t, 32, 64);
      if (g == 0) smx[w][i * 16 + fr] = t;
    }
    asm volatile("s_waitcnt lgkmcnt(0)" ::: "memory");
#pragma unroll
    for (int i = 0; i < 2; ++i)
#pragma unroll
      for (int r = 0; r < 4; ++r) {
        float inv = 1.0f / smx[w][i * 16 + 4 * g + r];
        int q = wq + i * 16 + 4 * g + r;
#pragma unroll
        for (int jd = 0; jd < 4; ++jd)
          Y[((size_t)b * SEQ + q) * N_EMBD + h * HDIM + jd * 16 + fr] =
              f2bf(acc_o[i][jd][r] * inv);
      }
  }
}

// ---------------- launcher ----------------
extern "C" void kernel_launch(void* const* d_in, const int* in_sizes, int n_in,
                              void* d_out, int out_size, void* d_ws, size_t ws_size,
                              hipStream_t stream) {
  (void)in_sizes; (void)n_in; (void)out_size; (void)ws_size;
  const float* x      = (const float*)d_in[0];
  const float* w_attn = (const float*)d_in[1];
  const float* b_attn = (const float*)d_in[2];
  const float* w_proj = (const float*)d_in[3];
  const float* b_proj = (const float*)d_in[4];
  float* out = (float*)d_out;

  char* ws = (char*)d_ws;
  size_t off = 0;
  auto carve = [&](size_t bytes) -> char* {
    char* p = ws + off;
    off += (bytes + 255) & ~(size_t)255;
    return p;
  };
  unsigned short* xb     = (unsigned short*)carve((size_t)MROWS * N_EMBD * 2);
  unsigned short* wTattn = (unsigned short*)carve((size_t)3 * N_EMBD * N_EMBD * 2);
  unsigned short* wTproj = (unsigned short*)carve((size_t)N_EMBD * N_EMBD * 2);
  unsigned short* Qb     = (unsigned short*)carve((size_t)MROWS * N_EMBD * 2);
  unsigned short* Kb     = (unsigned short*)carve((size_t)MROWS * N_EMBD * 2);
  unsigned short* VTb    = (unsigned short*)carve((size_t)MROWS * N_EMBD * 2);
  unsigned short* Yb     = (unsigned short*)carve((size_t)MROWS * N_EMBD * 2);
  carve(4096);

  cast_f32_bf16<<<dim3(MROWS * N_EMBD / 1024), 256, 0, stream>>>(x, xb, MROWS * N_EMBD);
  transpose_cast2<<<dim3(64, 16), 256, 0, stream>>>(w_attn, wTattn, w_proj, wTproj);
  gemm_qkv<<<dim3(1536), 256, 0, stream>>>(xb, wTattn, b_attn, Qb, Kb, VTb);
  attn_kernel<<<dim3(512), 256, 0, stream>>>(Qb, Kb, VTb, Yb);
  gemm_proj<<<dim3(512), 256, 0, stream>>>(Yb, wTproj, b_proj, out);
}